// Round 1
// baseline (812.133 us; speedup 1.0000x reference)
//
#include <hip/hip_runtime.h>
#include <hip/hip_bf16.h>

// Problem constants
#define B_ 8
#define L_ 2048
#define E_ 256
#define H_ 4
#define D_ 64

typedef __attribute__((ext_vector_type(8))) short short8;
typedef __attribute__((ext_vector_type(4))) float f32x4;

// f32 -> bf16 (RNE) bit pattern as short
static __device__ __forceinline__ short f2bs(float f) {
    unsigned u = __builtin_bit_cast(unsigned, f);
    u += 0x7FFFu + ((u >> 16) & 1u);
    return (short)(u >> 16);
}

// ---------------------------------------------------------------------------
// Kernel 1: weight prep.
//  blocks 0..255 (n = out-col): WkT[n][c]=Wk[c][n]; WpT[n][c]=Wp[c][n];
//    Wq2T[n][c] = sum_d Wq[c][h*64+d]*Wbil[d][e]   (h=n>>6, e=n&63)
//  block 256: bq2[n] = sum_d bq[h*64+d]*Wbil[d][e]
// ---------------------------------------------------------------------------
__global__ __launch_bounds__(256) void prep_kernel(
    const float* __restrict__ Wk, const float* __restrict__ Wq,
    const float* __restrict__ bq, const float* __restrict__ Wbil,
    const float* __restrict__ Wp,
    short* __restrict__ WkT, short* __restrict__ Wq2T,
    short* __restrict__ WpT, float* __restrict__ bq2) {
    const int n = blockIdx.x;
    const int t = threadIdx.x;
    if (n < 256) {
        WkT[n * 256 + t] = f2bs(Wk[t * 256 + n]);
        WpT[n * 256 + t] = f2bs(Wp[t * 256 + n]);
        const int h = n >> 6, e = n & 63;
        float acc = 0.f;
        #pragma unroll 8
        for (int d = 0; d < 64; ++d)
            acc += Wq[t * 256 + h * 64 + d] * Wbil[d * 64 + e];
        Wq2T[n * 256 + t] = f2bs(acc);
    } else {
        const int h = t >> 6, e = t & 63;
        float acc = 0.f;
        #pragma unroll 8
        for (int d = 0; d < 64; ++d)
            acc += bq[h * 64 + d] * Wbil[d * 64 + e];
        bq2[t] = acc;
    }
}

// ---------------------------------------------------------------------------
// Kernel 2: projections.  grid (256, 2): y==0 -> kx (writes kxb + kxTb),
// y==1 -> qw (writes qwb).  4 waves/WG, wave = 16 rows, full N=256.
// ---------------------------------------------------------------------------
__global__ __launch_bounds__(256) void proj_kernel(
    const float* __restrict__ xk, const float* __restrict__ xq,
    const short* __restrict__ WkT, const short* __restrict__ Wq2T,
    const float* __restrict__ bk, const float* __restrict__ bq2,
    short* __restrict__ kxb, short* __restrict__ kxTb,
    short* __restrict__ qwb) {
    const int sel = blockIdx.y;
    const float* A = sel ? xq : xk;
    const short* WT = sel ? Wq2T : WkT;
    const float* bias = sel ? bq2 : bk;

    const int w = threadIdx.x >> 6, lane = threadIdx.x & 63;
    const int lg = lane >> 4, lr = lane & 15;
    const int mbase = blockIdx.x * 64 + w * 16;
    const int m = mbase + lr;  // A-frag row for this lane

    // Load + convert the wave's whole A strip [16 x 256] as 8 K-frags.
    short8 afr[8];
    const float* arow = A + (size_t)m * 256 + lg * 8;
    #pragma unroll
    for (int kc = 0; kc < 8; ++kc) {
        float4 x0 = *reinterpret_cast<const float4*>(arow + kc * 32);
        float4 x1 = *reinterpret_cast<const float4*>(arow + kc * 32 + 4);
        short8 a;
        a[0] = f2bs(x0.x); a[1] = f2bs(x0.y); a[2] = f2bs(x0.z); a[3] = f2bs(x0.w);
        a[4] = f2bs(x1.x); a[5] = f2bs(x1.y); a[6] = f2bs(x1.z); a[7] = f2bs(x1.w);
        afr[kc] = a;
    }

    for (int nt = 0; nt < 16; ++nt) {
        f32x4 acc = {0.f, 0.f, 0.f, 0.f};
        const short* wrow = WT + (nt * 16 + lr) * 256 + lg * 8;
        #pragma unroll
        for (int kc = 0; kc < 8; ++kc) {
            short8 bfr = *reinterpret_cast<const short8*>(wrow + kc * 32);
            acc = __builtin_amdgcn_mfma_f32_16x16x32_bf16(afr[kc], bfr, acc, 0, 0, 0);
        }
        const int n = nt * 16 + lr;     // D col = lane&15
        const float bn = bias[n];
        const int h = n >> 6, d = n & 63;
        #pragma unroll
        for (int r = 0; r < 4; ++r) {
            const int gm = mbase + lg * 4 + r;  // D row = (lane>>4)*4+r
            const int bb = gm >> 11, ll = gm & 2047;
            const short sv = f2bs(acc[r] + bn);
            if (sel) {
                qwb[(((size_t)(bb * H_ + h)) * L_ + ll) * 64 + d] = sv;
            } else {
                kxb[(((size_t)(bb * H_ + h)) * L_ + ll) * 64 + d] = sv;
                kxTb[(((size_t)(bb * H_ + h)) * 64 + d) * L_ + ll] = sv;
            }
        }
    }
}

// ---------------------------------------------------------------------------
// Kernel 3: fused score -> softmax -> attn write -> PV.
// grid (128 qtiles, H, B), 512 threads (8 waves). Wave w owns k-cols
// [w*256, w*256+256).  Scores for 16 q-rows live in regs (64 f32/lane).
// ---------------------------------------------------------------------------
__global__ __launch_bounds__(512) void attn_kernel(
    const short* __restrict__ kxb, const short* __restrict__ kxTb,
    const short* __restrict__ qwb,
    float* __restrict__ attn, short* __restrict__ out_pre) {
    __shared__ float red[2][16][8];
    __shared__ __align__(16) char Pb[8 * 4096];

    const int w = threadIdx.x >> 6, lane = threadIdx.x & 63;
    const int lg = lane >> 4, lr = lane & 15;
    const int qbase = blockIdx.x * 16;
    const int h = blockIdx.y, b = blockIdx.z;
    const int colbase = w * 256;

    const short* kx  = kxb  + ((size_t)(b * H_ + h)) * L_ * 64;
    const short* kxT = kxTb + ((size_t)(b * H_ + h)) * 64 * L_;
    const short* qw  = qwb  + (((size_t)(b * H_ + h)) * L_ + qbase) * 64;

    // score A-frags (qw rows = q-tile)
    short8 aq0 = *reinterpret_cast<const short8*>(qw + lr * 64 + lg * 8);
    short8 aq1 = *reinterpret_cast<const short8*>(qw + lr * 64 + 32 + lg * 8);

    // ---- scores: 16 tiles of 16x16, K=64 ----
    f32x4 p[16];
    #pragma unroll
    for (int t = 0; t < 16; ++t) {
        const short* krow = kx + (size_t)(colbase + t * 16 + lr) * 64 + lg * 8;
        short8 b0 = *reinterpret_cast<const short8*>(krow);
        short8 b1 = *reinterpret_cast<const short8*>(krow + 32);
        f32x4 acc = {0.f, 0.f, 0.f, 0.f};
        acc = __builtin_amdgcn_mfma_f32_16x16x32_bf16(aq0, b0, acc, 0, 0, 0);
        acc = __builtin_amdgcn_mfma_f32_16x16x32_bf16(aq1, b1, acc, 0, 0, 0);
        p[t] = acc;
    }

    // ---- row max: per-lane over tiles, shfl over 16-lane group, LDS x-wave
    float mx[4];
    #pragma unroll
    for (int r = 0; r < 4; ++r) {
        float m0 = p[0][r];
        #pragma unroll
        for (int t = 1; t < 16; ++t) m0 = fmaxf(m0, p[t][r]);
        #pragma unroll
        for (int s = 1; s < 16; s <<= 1) m0 = fmaxf(m0, __shfl_xor(m0, s));
        mx[r] = m0;
    }
    if (lr == 0) {
        #pragma unroll
        for (int r = 0; r < 4; ++r) red[0][lg * 4 + r][w] = mx[r];
    }
    __syncthreads();
    float gmx[4];
    #pragma unroll
    for (int r = 0; r < 4; ++r) {
        float m0 = red[0][lg * 4 + r][0];
        #pragma unroll
        for (int ww = 1; ww < 8; ++ww) m0 = fmaxf(m0, red[0][lg * 4 + r][ww]);
        gmx[r] = m0;
    }

    // ---- exp + row sum ----
    float ls[4] = {0.f, 0.f, 0.f, 0.f};
    #pragma unroll
    for (int t = 0; t < 16; ++t) {
        #pragma unroll
        for (int r = 0; r < 4; ++r) {
            float e = exp2f((p[t][r] - gmx[r]) * 1.44269504088896f);
            p[t][r] = e;
            ls[r] += e;
        }
    }
    #pragma unroll
    for (int r = 0; r < 4; ++r) {
        float s0 = ls[r];
        #pragma unroll
        for (int s = 1; s < 16; s <<= 1) s0 += __shfl_xor(s0, s);
        ls[r] = s0;
    }
    if (lr == 0) {
        #pragma unroll
        for (int r = 0; r < 4; ++r) red[1][lg * 4 + r][w] = ls[r];
    }
    __syncthreads();
    float inv[4];
    #pragma unroll
    for (int r = 0; r < 4; ++r) {
        float s0 = 0.f;
        #pragma unroll
        for (int ww = 0; ww < 8; ++ww) s0 += red[1][lg * 4 + r][ww];
        inv[r] = 1.0f / s0;
    }

    // ---- attn write (normalized), nontemporal streaming f32 ----
    #pragma unroll
    for (int r = 0; r < 4; ++r) {
        float* arow = attn +
            ((size_t)((h * B_ + b) * L_ + qbase + lg * 4 + r)) * L_ + colbase + lr;
        const float iv = inv[r];
        #pragma unroll
        for (int t = 0; t < 16; ++t)
            __builtin_nontemporal_store(p[t][r] * iv, arow + t * 16);
    }

    // ---- PV: two 128-col halves through swizzled LDS P buffer ----
    f32x4 oacc[4];
    #pragma unroll
    for (int dt = 0; dt < 4; ++dt) oacc[dt] = f32x4{0.f, 0.f, 0.f, 0.f};
    char* myP = Pb + w * 4096;  // own wave's [16][128] bf16, XOR-swizzled

    #pragma unroll
    for (int hh = 0; hh < 2; ++hh) {
        #pragma unroll
        for (int tt = 0; tt < 8; ++tt) {
            const int t = hh * 8 + tt;
            #pragma unroll
            for (int r = 0; r < 4; ++r) {
                const int R = lg * 4 + r;
                const int byte = R * 256 + (((tt * 16 + lr) * 2) ^ (R << 4));
                *reinterpret_cast<short*>(myP + byte) = f2bs(p[t][r]);
            }
        }
        #pragma unroll
        for (int kb = 0; kb < 4; ++kb) {
            const int byteA = lr * 256 + (((kb * 32 + lg * 8) * 2) ^ (lr << 4));
            short8 aP = *reinterpret_cast<const short8*>(myP + byteA);
            const short* kcolp = kxT + colbase + hh * 128 + kb * 32 + lg * 8;
            #pragma unroll
            for (int dt = 0; dt < 4; ++dt) {
                short8 bv = *reinterpret_cast<const short8*>(
                    kcolp + (size_t)(dt * 16 + lr) * L_);
                oacc[dt] = __builtin_amdgcn_mfma_f32_16x16x32_bf16(aP, bv, oacc[dt], 0, 0, 0);
            }
        }
    }

    // ---- per-wave PV partials into own LDS region as f32 [16][64] ----
    #pragma unroll
    for (int dt = 0; dt < 4; ++dt)
        #pragma unroll
        for (int r = 0; r < 4; ++r)
            *reinterpret_cast<float*>(myP + ((lg * 4 + r) * 64 + dt * 16 + lr) * 4) =
                oacc[dt][r];
    __syncthreads();

    // ---- cross-wave reduce + normalize + out_pre (bf16) ----
    {
        const int e0 = threadIdx.x * 2;      // 1024 elements, 2 per thread
        const int q = e0 >> 6;
        float s0 = 0.f, s1 = 0.f;
        #pragma unroll
        for (int ww = 0; ww < 8; ++ww) {
            const float* pp = reinterpret_cast<const float*>(Pb + ww * 4096) + e0;
            s0 += pp[0];
            s1 += pp[1];
        }
        float sm = 0.f;
        #pragma unroll
        for (int ww = 0; ww < 8; ++ww) sm += red[1][q][ww];
        const float iv = 1.0f / sm;
        const size_t o = ((size_t)(b * L_ + qbase + q)) * 256 + h * 64 + (e0 & 63);
        out_pre[o] = f2bs(s0 * iv);
        out_pre[o + 1] = f2bs(s1 * iv);
    }
}

// ---------------------------------------------------------------------------
// Kernel 4: out = out_pre(bf16) @ Wp + bp  -> f32
// ---------------------------------------------------------------------------
__global__ __launch_bounds__(256) void outproj_kernel(
    const short* __restrict__ out_pre, const short* __restrict__ WpT,
    const float* __restrict__ bp, float* __restrict__ out) {
    const int w = threadIdx.x >> 6, lane = threadIdx.x & 63;
    const int lg = lane >> 4, lr = lane & 15;
    const int mbase = blockIdx.x * 64 + w * 16;

    short8 afr[8];
    const short* arow = out_pre + (size_t)(mbase + lr) * 256 + lg * 8;
    #pragma unroll
    for (int kc = 0; kc < 8; ++kc)
        afr[kc] = *reinterpret_cast<const short8*>(arow + kc * 32);

    for (int nt = 0; nt < 16; ++nt) {
        f32x4 acc = {0.f, 0.f, 0.f, 0.f};
        const short* wrow = WpT + (nt * 16 + lr) * 256 + lg * 8;
        #pragma unroll
        for (int kc = 0; kc < 8; ++kc) {
            short8 bfr = *reinterpret_cast<const short8*>(wrow + kc * 32);
            acc = __builtin_amdgcn_mfma_f32_16x16x32_bf16(afr[kc], bfr, acc, 0, 0, 0);
        }
        const float bn = bp[nt * 16 + lr];
        #pragma unroll
        for (int r = 0; r < 4; ++r)
            out[(size_t)(mbase + lg * 4 + r) * 256 + nt * 16 + lr] = acc[r] + bn;
    }
}

// ---------------------------------------------------------------------------
extern "C" void kernel_launch(void* const* d_in, const int* in_sizes, int n_in,
                              void* d_out, int out_size, void* d_ws, size_t ws_size,
                              hipStream_t stream) {
    const float* k    = (const float*)d_in[0];
    const float* q    = (const float*)d_in[1];
    const float* Wk   = (const float*)d_in[2];
    const float* bk   = (const float*)d_in[3];
    const float* Wq   = (const float*)d_in[4];
    const float* bq   = (const float*)d_in[5];
    const float* Wbil = (const float*)d_in[6];
    const float* Wp   = (const float*)d_in[7];
    const float* bp   = (const float*)d_in[8];

    char* ws = (char*)d_ws;
    // workspace layout (bytes)
    short* WkT   = (short*)(ws + 0);                 // 128 KB
    short* Wq2T  = (short*)(ws + 131072);            // 128 KB
    short* WpT   = (short*)(ws + 262144);            // 128 KB
    float* bq2   = (float*)(ws + 393216);            // 1 KB
    short* kxb   = (short*)(ws + 394240);            // 8 MB   [B,H,L,D]
    short* kxTb  = (short*)(ws + 394240 + 8388608);  // 8 MB   [B,H,D,L]
    short* qwb   = (short*)(ws + 394240 + 2 * 8388608); // 8 MB [B,H,L,D]
    short* opre  = (short*)(ws + 394240 + 3 * 8388608); // 8 MB [B*L, 256]

    float* out  = (float*)d_out;
    float* attn = out + (size_t)B_ * L_ * E_;  // outputs concatenated: out, attn

    prep_kernel<<<257, 256, 0, stream>>>(Wk, Wq, bq, Wbil, Wp, WkT, Wq2T, WpT, bq2);
    proj_kernel<<<dim3(256, 2), 256, 0, stream>>>(k, q, WkT, Wq2T, bk, bq2,
                                                  kxb, kxTb, qwb);
    attn_kernel<<<dim3(128, H_, B_), 512, 0, stream>>>(kxb, kxTb, qwb, attn, opre);
    outproj_kernel<<<256, 256, 0, stream>>>(opre, WpT, bp, out);
}